// Round 11
// baseline (174.294 us; speedup 1.0000x reference)
//
#include <hip/hip_runtime.h>
#include <math.h>

#define Bdim 64
#define Ndim 512
#define Ddim 16
#define Kdim 16
#define Edim 128
#define LN_EPS 1e-5f

#define PTS   2     // points per block, ONE point per wave
#define NT    8     // 16-wide N tiles over E=128
#define KS2   4     // 32-deep K steps over E=128

typedef __attribute__((ext_vector_type(8))) short bf16x8;
typedef __attribute__((ext_vector_type(4))) float f32x4;
typedef __attribute__((ext_vector_type(2))) float f32x2;

#if __has_builtin(__builtin_amdgcn_exp2f)
#define EXP2F __builtin_amdgcn_exp2f
#else
#define EXP2F exp2f
#endif

// ---- DPP helpers (pure VALU, no LDS) ----
// row_ror:N = 0x120|N ; ROW_BCAST15 = 0x142 ; ROW_BCAST31 = 0x143
template<int CTRL>
__device__ __forceinline__ unsigned dpp_u32(unsigned v) {
    return (unsigned)__builtin_amdgcn_update_dpp(0, (int)v, CTRL, 0xF, 0xF, true);
}
// keep-variant: lanes with no DPP source keep their own value (old = src, bound_ctrl=0)
template<int CTRL>
__device__ __forceinline__ unsigned dpp_u32_keep(unsigned v) {
    return (unsigned)__builtin_amdgcn_update_dpp((int)v, (int)v, CTRL, 0xF, 0xF, false);
}
template<int CTRL>
__device__ __forceinline__ float dpp_f32(float v) {
    return __int_as_float(__builtin_amdgcn_update_dpp(0, __float_as_int(v), CTRL, 0xF, 0xF, true));
}
__device__ __forceinline__ unsigned min_u32(unsigned a, unsigned b) { return (b < a) ? b : a; }

// RNE float -> bf16 bits (used only in the tiny pack kernel)
__device__ __forceinline__ unsigned short f2bf(float f) {
    unsigned u = __float_as_uint(f);
    unsigned r = (u + 0x7FFFu + ((u >> 16) & 1u)) >> 16;
    return (unsigned short)r;
}

// HW packed f32->bf16 (RNE): lo16 = bf16(a), hi16 = bf16(b)
__device__ __forceinline__ unsigned cvt_pk_bf16(float a, float b) {
    unsigned r;
    asm("v_cvt_pk_bf16_f32 %0, %1, %2" : "=v"(r) : "v"(a), "v"(b));
    return r;
}

// packed GELU (tanh-form via sigmoid, exp folded to native 2^x):
// gelu(x) ~= x * rcp(1 + 2^(x * (-2.30220821 - 0.10294324 x^2)))
__device__ __forceinline__ f32x2 gelu2(f32x2 x) {
    f32x2 x2 = x * x;
    f32x2 t  = x2 * (f32x2){-0.10294324f, -0.10294324f}
                  + (f32x2){-2.30220821f, -2.30220821f};
    f32x2 z  = x * t;
    f32x2 e  = { EXP2F(z.x), EXP2F(z.y) };
    f32x2 d  = e + (f32x2){1.0f, 1.0f};
    f32x2 r  = { __builtin_amdgcn_rcpf(d.x), __builtin_amdgcn_rcpf(d.y) };
    return x * r;
}

// ---------------- weight pre-pack ----------------
// wp[0..36863]  : bf16 B-fragments (layout as before)
// fp32 at float index 18432 (byte 73728): gbe pairs, float2
//   gbe[((lay*8 + nt)*16 + cl)] = { g[nt*16+cl], be[nt*16+cl] }   (768 floats)
__global__ __launch_bounds__(256) void pack_w_kernel(
    const float* __restrict__ W1, const float* __restrict__ W2,
    const float* __restrict__ W3,
    const float* __restrict__ g1, const float* __restrict__ be1,
    const float* __restrict__ g2, const float* __restrict__ be2,
    const float* __restrict__ g3, const float* __restrict__ be3,
    unsigned short* __restrict__ wp)
{
    int idx = blockIdx.x * 256 + threadIdx.x;
    if (idx >= 37632) return;
    if (idx < 4096) {
        int t = idx;
        int nt = t >> 9, l = (t >> 3) & 63, j = t & 7;
        int k = 8 * (l >> 4) + j, n = nt * 16 + (l & 15);
        wp[idx] = f2bf(W1[k * Edim + n]);
    } else if (idx < 20480) {
        int t = idx - 4096;
        int nt = t >> 11, ks = (t >> 9) & 3, l = (t >> 3) & 63, j = t & 7;
        int k = ks * 32 + 8 * (l >> 4) + j, n = nt * 16 + (l & 15);
        wp[idx] = f2bf(W2[k * Edim + n]);
    } else if (idx < 36864) {
        int t = idx - 20480;
        int nt = t >> 11, ks = (t >> 9) & 3, l = (t >> 3) & 63, j = t & 7;
        int k = ks * 32 + 8 * (l >> 4) + j, n = nt * 16 + (l & 15);
        wp[idx] = f2bf(W3[k * Edim + n]);
    } else {
        int t = idx - 36864;              // 0..767
        int lay = t >> 8;                 // 256 floats per layer
        int e   = t & 255;
        int nt  = e >> 5;                 // 32 per nt (16 cl x 2 comp)
        int cl  = (e >> 1) & 15;
        int comp = e & 1;
        const float* g  = (lay == 0) ? g1  : (lay == 1) ? g2  : g3;
        const float* be = (lay == 0) ? be1 : (lay == 1) ? be2 : be3;
        float v = comp ? be[nt*16 + cl] : g[nt*16 + cl];
        ((float*)wp)[18432 + t] = v;
    }
}

// LayerNorm + GELU on the wave-private accumulator (one point).
// D layout per 16x16 tile: value j of lane l is H[row = 4*(l>>4) + j][col = nt*16 + (l&15)]
// Row-reduction via packed DPP rot-adds; elementwise math on packed f32x2 (v_pk_*).
// gbeL: per-layer {gamma, beta} pairs, indexed [nt*16 + cl].
__device__ __forceinline__ void ln_gelu_acc(
    f32x4 acc[NT], const float2* __restrict__ gbeL, int lane)
{
    const int cl = lane & 15;
    f32x2 s01 = {0.f,0.f}, s23 = {0.f,0.f}, q01 = {0.f,0.f}, q23 = {0.f,0.f};
    #pragma unroll
    for (int nt = 0; nt < NT; ++nt) {
        f32x2 a01 = { acc[nt][0], acc[nt][1] };
        f32x2 a23 = { acc[nt][2], acc[nt][3] };
        s01 += a01;  q01 += a01 * a01;      // pk_add / pk_fma
        s23 += a23;  q23 += a23 * a23;
    }
    #define ROTSTEP(C) {                                                     \
        f32x2 t_;                                                            \
        t_.x = dpp_f32<C>(s01.x); t_.y = dpp_f32<C>(s01.y); s01 += t_;       \
        t_.x = dpp_f32<C>(s23.x); t_.y = dpp_f32<C>(s23.y); s23 += t_;       \
        t_.x = dpp_f32<C>(q01.x); t_.y = dpp_f32<C>(q01.y); q01 += t_;       \
        t_.x = dpp_f32<C>(q23.x); t_.y = dpp_f32<C>(q23.y); q23 += t_;       \
    }
    ROTSTEP(0x121) ROTSTEP(0x122) ROTSTEP(0x124) ROTSTEP(0x128)
    #undef ROTSTEP

    const f32x2 inv128 = { 1.0f/128.0f, 1.0f/128.0f };
    f32x2 m01 = s01 * inv128, m23 = s23 * inv128;
    f32x2 v01 = q01 * inv128 - m01 * m01;
    f32x2 v23 = q23 * inv128 - m23 * m23;
    f32x2 r01 = { __builtin_amdgcn_rsqf(v01.x + LN_EPS), __builtin_amdgcn_rsqf(v01.y + LN_EPS) };
    f32x2 r23 = { __builtin_amdgcn_rsqf(v23.x + LN_EPS), __builtin_amdgcn_rsqf(v23.y + LN_EPS) };

    #pragma unroll
    for (int nt = 0; nt < NT; ++nt) {
        const float2 gb = gbeL[nt*16 + cl];       // one dwordx2: {gamma, beta}
        const f32x2 gg = { gb.x, gb.x }, bb = { gb.y, gb.y };
        f32x2 a01 = { acc[nt][0], acc[nt][1] };
        f32x2 a23 = { acc[nt][2], acc[nt][3] };
        f32x2 w01 = (a01 - m01) * r01;
        f32x2 w23 = (a23 - m23) * r23;
        w01 = w01 * gg + bb;                // pk_fma
        w23 = w23 * gg + bb;
        w01 = gelu2(w01);
        w23 = gelu2(w23);
        acc[nt][0] = w01.x; acc[nt][1] = w01.y;
        acc[nt][2] = w23.x; acc[nt][3] = w23.y;
    }
}

// store acc (bf16 via HW cvt_pk) to swizzled H:
// elem col c of row r lives at r*128 + ((c>>3 ^ (r&7))<<3) + (c&7)
__device__ __forceinline__ void store_h(
    const f32x4 acc[NT], unsigned short* __restrict__ s_h, int wave, int lane)
{
    const int cl = lane & 15, gq = lane >> 4;
    const int rbase = 16*wave + 4*gq;
    #pragma unroll
    for (int nt = 0; nt < NT; ++nt) {
        const int col = nt*16 + cl;
        const int cb  = col >> 3;
        const unsigned r01 = cvt_pk_bf16(acc[nt][0], acc[nt][1]);
        const unsigned r23 = cvt_pk_bf16(acc[nt][2], acc[nt][3]);
        const int a0 = (rbase+0)*128 + ((cb ^ ((rbase+0) & 7)) << 3) + (col & 7);
        const int a1 = (rbase+1)*128 + ((cb ^ ((rbase+1) & 7)) << 3) + (col & 7);
        const int a2 = (rbase+2)*128 + ((cb ^ ((rbase+2) & 7)) << 3) + (col & 7);
        const int a3 = (rbase+3)*128 + ((cb ^ ((rbase+3) & 7)) << 3) + (col & 7);
        s_h[a0] = (unsigned short)(r01 & 0xFFFFu);
        s_h[a1] = (unsigned short)(r01 >> 16);
        s_h[a2] = (unsigned short)(r23 & 0xFFFFu);
        s_h[a3] = (unsigned short)(r23 >> 16);
    }
}

__global__ __launch_bounds__(128, 5) void edgeconv_mfma(
    const float* __restrict__ x,
    const unsigned short* __restrict__ wp,
    const float* __restrict__ b1, const float* __restrict__ b2,
    const float* __restrict__ b3,
    float* __restrict__ out)
{
    const int tid  = threadIdx.x;
    const int wave = tid >> 6, lane = tid & 63;
    const int bp = blockIdx.x;
    const int b  = bp >> 8;              // 256 blocks per batch element
    const int n0 = (bp & 255) * PTS;
    const int n  = n0 + wave;            // this wave's point

    // only LDS: wave-private H rows (wave w owns rows 16w..16w+15). No barriers anywhere.
    __shared__ __align__(16) unsigned short s_h[32 * 128];         // 8 KB, XOR-swizzled

    const float* __restrict__ xb = x + (size_t)b * (Ndim * Ddim);
    const float2* __restrict__ gbep = (const float2*)((const float*)wp + 18432);
    const int cl = lane & 15, gq = lane >> 4;

    // ---- KNN for this wave's point. Exact fp32 mul/mul/add; lex (d2, idx) order.
    //      Lane cl captures the cl-th selected neighbor index in my_nb.
    unsigned my_nb = 0;
    {
        const float qx = xb[n * Ddim + 8], qy = xb[n * Ddim + 9];
        unsigned long long key[8];
        #pragma unroll
        for (int c = 0; c < 8; ++c) {
            int j = c * 64 + lane;
            const float2 p2 = *(const float2*)(xb + j * Ddim + 8);
            float dx = __fsub_rn(qx, p2.x);
            float dy = __fsub_rn(qy, p2.y);
            float d2 = __fadd_rn(__fmul_rn(dx,dx), __fmul_rn(dy,dy));
            key[c] = ((unsigned long long)__float_as_uint(d2) << 32) | (unsigned)j;
        }
        // lane-local ascending sort of 8 keys (Batcher odd-even mergesort, 19 CE)
        #define CE(A,B) { bool c_ = key[A] < key[B];                          \
                          unsigned long long lo_ = c_ ? key[A] : key[B];      \
                          unsigned long long hi_ = c_ ? key[B] : key[A];      \
                          key[A] = lo_; key[B] = hi_; }
        CE(0,1) CE(2,3) CE(4,5) CE(6,7)
        CE(0,2) CE(1,3) CE(4,6) CE(5,7)
        CE(1,2) CE(5,6)
        CE(0,4) CE(1,5) CE(2,6) CE(3,7)
        CE(2,4) CE(3,5)
        CE(1,2) CE(3,4) CE(5,6)
        #undef CE

        unsigned d2h[8], idxh[8];
        #pragma unroll
        for (int c = 0; c < 8; ++c) {
            d2h[c]  = (unsigned)(key[c] >> 32);
            idxh[c] = (unsigned)key[c];
        }

        #pragma unroll
        for (int sel = 0; sel < Kdim; ++sel) {
            // wave-min of head d2: u32 only (1 v_min_u32 per stage)
            unsigned m = d2h[0];
            m = min_u32(m, dpp_u32<0x121>(m));
            m = min_u32(m, dpp_u32<0x122>(m));
            m = min_u32(m, dpp_u32<0x124>(m));
            m = min_u32(m, dpp_u32<0x128>(m));
            m = min_u32(m, dpp_u32_keep<0x142>(m));   // row1/3 <- min with row0/2
            m = min_u32(m, dpp_u32_keep<0x143>(m));   // upper half <- min with lane31
            const unsigned gmin = (unsigned)__builtin_amdgcn_readlane((int)m, 63);

            // tie resolution: wave-uniform branch, multi-tie is ~1e-4 rare
            const unsigned long long tied = __ballot(d2h[0] == gmin);
            unsigned widx;
            if (__popcll(tied) == 1) {
                const int s = (int)(__ffsll((long long)tied) - 1);
                widx = (unsigned)__builtin_amdgcn_readlane((int)idxh[0], s);
            } else {
                unsigned t = (d2h[0] == gmin) ? idxh[0] : 0xFFFFFFFFu;
                t = min_u32(t, dpp_u32<0x121>(t));
                t = min_u32(t, dpp_u32<0x122>(t));
                t = min_u32(t, dpp_u32<0x124>(t));
                t = min_u32(t, dpp_u32<0x128>(t));
                t = min_u32(t, dpp_u32_keep<0x142>(t));
                t = min_u32(t, dpp_u32_keep<0x143>(t));
                widx = (unsigned)__builtin_amdgcn_readlane((int)t, 63);
            }
            if ((lane & 15) == sel) my_nb = widx;     // capture in all 4 quads
            if (sel < Kdim - 1) {
                if (d2h[0] == gmin && idxh[0] == widx) {   // unique owner pops head
                    d2h[0]=d2h[1]; d2h[1]=d2h[2]; d2h[2]=d2h[3]; d2h[3]=d2h[4];
                    d2h[4]=d2h[5]; d2h[5]=d2h[6]; d2h[6]=d2h[7]; d2h[7]=0xFFFFFFFFu;
                    idxh[0]=idxh[1]; idxh[1]=idxh[2]; idxh[2]=idxh[3]; idxh[3]=idxh[4];
                    idxh[4]=idxh[5]; idxh[5]=idxh[6]; idxh[6]=idxh[7];
                }
            }
        }
    }

    f32x4 acc[NT];

    // ================= Layer 1: feats(16x32) @ W1, A-fragment built in registers =================
    {
        const int off8 = (gq & 1) * 8;
        const float* pc = xb + n * Ddim + off8;
        const float* pn = xb + (int)my_nb * Ddim + off8;
        float4 c0 = *(const float4*)(pc);
        float4 c1 = *(const float4*)(pc + 4);
        float4 v0 = *(const float4*)(pn);
        float4 v1 = *(const float4*)(pn + 4);
        const bool diff = (gq >= 2);
        float e0 = diff ? (v0.x - c0.x) : c0.x;
        float e1 = diff ? (v0.y - c0.y) : c0.y;
        float e2 = diff ? (v0.z - c0.z) : c0.z;
        float e3 = diff ? (v0.w - c0.w) : c0.w;
        float e4 = diff ? (v1.x - c1.x) : c1.x;
        float e5 = diff ? (v1.y - c1.y) : c1.y;
        float e6 = diff ? (v1.z - c1.z) : c1.z;
        float e7 = diff ? (v1.w - c1.w) : c1.w;
        union { unsigned u[4]; bf16x8 v; } a1u;
        a1u.u[0] = cvt_pk_bf16(e0, e1);
        a1u.u[1] = cvt_pk_bf16(e2, e3);
        a1u.u[2] = cvt_pk_bf16(e4, e5);
        a1u.u[3] = cvt_pk_bf16(e6, e7);
        const bf16x8 a1 = a1u.v;

        #pragma unroll
        for (int nt = 0; nt < NT; ++nt) {
            const float bv = b1[nt*16 + cl];
            bf16x8 bfr = *(const bf16x8*)(wp + (nt*64 + lane)*8);
            f32x4 c = {bv, bv, bv, bv};
            acc[nt] = __builtin_amdgcn_mfma_f32_16x16x32_bf16(a1, bfr, c, 0, 0, 0);
        }
    }
    ln_gelu_acc(acc, gbep, lane);
    store_h(acc, s_h, wave, lane);

    // ================= Layers 2 and 3: H(16x128) @ W(128x128) =================
    #pragma unroll 1
    for (int layer = 0; layer < 2; ++layer) {
        const unsigned short* wpL = wp + (layer == 0 ? 4096 : 20480);
        const float* bL = (layer == 0) ? b2 : b3;
        const float2* gbeL = gbep + (layer == 0 ? 128 : 256);

        bf16x8 a[KS2];
        {
            const int row = 16*wave + cl;
            #pragma unroll
            for (int ks = 0; ks < KS2; ++ks) {
                const int cb = ks*4 + gq;
                a[ks] = *(const bf16x8*)(&s_h[row*128 + ((cb ^ (row & 7)) << 3)]);
            }
        }
        #pragma unroll
        for (int nt = 0; nt < NT; ++nt) {
            const float bv = bL[nt*16 + cl];
            f32x4 c = {bv, bv, bv, bv};
            #pragma unroll
            for (int ks = 0; ks < KS2; ++ks) {
                bf16x8 bfr = *(const bf16x8*)(wpL + ((nt*KS2 + ks)*64 + lane)*8);
                c = __builtin_amdgcn_mfma_f32_16x16x32_bf16(a[ks], bfr, c, 0, 0, 0);
            }
            acc[nt] = c;
        }
        ln_gelu_acc(acc, gbeL, lane);
        if (layer == 0) store_h(acc, s_h, wave, lane);
    }

    // ================= mean over K=16 rows, write out =================
    #pragma unroll
    for (int nt = 0; nt < NT; ++nt) {
        f32x2 p = { acc[nt][0], acc[nt][1] };
        f32x2 q = { acc[nt][2], acc[nt][3] };
        f32x2 h = p + q;                    // pk_add
        float sv = h.x + h.y;
        sv += __shfl_xor(sv, 16, 64);
        sv += __shfl_xor(sv, 32, 64);
        if (gq == (nt >> 1))    // 16 lanes of the owning quad write 64B
            out[((size_t)b * Ndim + n) * Edim + nt*16 + cl] = sv * (1.0f/16.0f);
    }
}

extern "C" void kernel_launch(void* const* d_in, const int* in_sizes, int n_in,
                              void* d_out, int out_size, void* d_ws, size_t ws_size,
                              hipStream_t stream)
{
    const float* x   = (const float*)d_in[0];
    const float* W1  = (const float*)d_in[1];
    const float* b1  = (const float*)d_in[2];
    const float* g1  = (const float*)d_in[3];
    const float* be1 = (const float*)d_in[4];
    const float* W2  = (const float*)d_in[5];
    const float* b2  = (const float*)d_in[6];
    const float* g2  = (const float*)d_in[7];
    const float* be2 = (const float*)d_in[8];
    const float* W3  = (const float*)d_in[9];
    const float* b3  = (const float*)d_in[10];
    const float* g3  = (const float*)d_in[11];
    const float* be3 = (const float*)d_in[12];
    float* out = (float*)d_out;
    unsigned short* wp = (unsigned short*)d_ws;

    hipLaunchKernelGGL(pack_w_kernel, dim3(147), dim3(256), 0, stream,
                       W1, W2, W3, g1, be1, g2, be2, g3, be3, wp);
    hipLaunchKernelGGL(edgeconv_mfma, dim3((Bdim * Ndim) / PTS), dim3(128), 0, stream,
                       x, wp, b1, b2, b3, out);
}

// Round 12
// 172.043 us; speedup vs baseline: 1.0131x; 1.0131x over previous
//
#include <hip/hip_runtime.h>
#include <math.h>

#define Bdim 64
#define Ndim 512
#define Ddim 16
#define Kdim 16
#define Edim 128
#define LN_EPS 1e-5f

#define PTS   2     // points per block, ONE point per wave
#define NT    8     // 16-wide N tiles over E=128
#define KS2   4     // 32-deep K steps over E=128

typedef __attribute__((ext_vector_type(8))) short bf16x8;
typedef __attribute__((ext_vector_type(4))) float f32x4;
typedef __attribute__((ext_vector_type(2))) float f32x2;

// ---- DPP helpers (pure VALU, no LDS) ----
// row_ror:N = 0x120|N ; ROW_BCAST15 = 0x142 ; ROW_BCAST31 = 0x143
template<int CTRL>
__device__ __forceinline__ unsigned dpp_u32(unsigned v) {
    return (unsigned)__builtin_amdgcn_update_dpp(0, (int)v, CTRL, 0xF, 0xF, true);
}
// keep-variant: lanes with no DPP source keep their own value (old = src, bound_ctrl=0)
template<int CTRL>
__device__ __forceinline__ unsigned dpp_u32_keep(unsigned v) {
    return (unsigned)__builtin_amdgcn_update_dpp((int)v, (int)v, CTRL, 0xF, 0xF, false);
}
template<int CTRL>
__device__ __forceinline__ float dpp_f32(float v) {
    return __int_as_float(__builtin_amdgcn_update_dpp(0, __float_as_int(v), CTRL, 0xF, 0xF, true));
}
__device__ __forceinline__ unsigned min_u32(unsigned a, unsigned b) { return (b < a) ? b : a; }

// RNE float -> bf16 bits (used only in the tiny pack kernel)
__device__ __forceinline__ unsigned short f2bf(float f) {
    unsigned u = __float_as_uint(f);
    unsigned r = (u + 0x7FFFu + ((u >> 16) & 1u)) >> 16;
    return (unsigned short)r;
}

// HW packed f32->bf16 (RNE): lo16 = bf16(a), hi16 = bf16(b)
__device__ __forceinline__ unsigned cvt_pk_bf16(float a, float b) {
    unsigned r;
    asm("v_cvt_pk_bf16_f32 %0, %1, %2" : "=v"(r) : "v"(a), "v"(b));
    return r;
}

// packed GELU, tanh-form with Pade [5/4] tanh (NO exp):
//   y = 0.7978845608 x + 0.0356774081 x^3 ; u = y^2
//   tanh(y) ~= y*(945 + 105u + u^2) / (945 + 420u + 15u^2)   [continued fraction]
//   |err| <= ~4e-4 for y<=3; ratio >1 only for y>3.7 -> clamp to [-1,1]
//   gelu = 0.5x(1+t). Max abs gelu error ~1.6e-3, below bf16 noise floor.
__device__ __forceinline__ f32x2 gelu2(f32x2 x) {
    f32x2 x2  = x * x;
    f32x2 y   = x * (x2 * (f32x2){0.0356774081f, 0.0356774081f}
                        + (f32x2){0.7978845608f, 0.7978845608f});
    f32x2 u   = y * y;
    f32x2 num = y * (u * (u + (f32x2){105.f, 105.f}) + (f32x2){945.f, 945.f});
    f32x2 den = u * (u * (f32x2){15.f, 15.f} + (f32x2){420.f, 420.f})
                  + (f32x2){945.f, 945.f};
    f32x2 r   = { __builtin_amdgcn_rcpf(den.x), __builtin_amdgcn_rcpf(den.y) };
    f32x2 t   = num * r;
    t.x = fminf(fmaxf(t.x, -1.0f), 1.0f);
    t.y = fminf(fmaxf(t.y, -1.0f), 1.0f);
    f32x2 h = x * (f32x2){0.5f, 0.5f};
    return h * t + h;
}

// ---------------- weight pre-pack ----------------
// wp[0..36863]  : bf16 B-fragments (layout as before)
// fp32 at float index 18432 (byte 73728): gbe pairs, float2
//   gbe[((lay*8 + nt)*16 + cl)] = { g[nt*16+cl], be[nt*16+cl] }   (768 floats)
__global__ __launch_bounds__(256) void pack_w_kernel(
    const float* __restrict__ W1, const float* __restrict__ W2,
    const float* __restrict__ W3,
    const float* __restrict__ g1, const float* __restrict__ be1,
    const float* __restrict__ g2, const float* __restrict__ be2,
    const float* __restrict__ g3, const float* __restrict__ be3,
    unsigned short* __restrict__ wp)
{
    int idx = blockIdx.x * 256 + threadIdx.x;
    if (idx >= 37632) return;
    if (idx < 4096) {
        int t = idx;
        int nt = t >> 9, l = (t >> 3) & 63, j = t & 7;
        int k = 8 * (l >> 4) + j, n = nt * 16 + (l & 15);
        wp[idx] = f2bf(W1[k * Edim + n]);
    } else if (idx < 20480) {
        int t = idx - 4096;
        int nt = t >> 11, ks = (t >> 9) & 3, l = (t >> 3) & 63, j = t & 7;
        int k = ks * 32 + 8 * (l >> 4) + j, n = nt * 16 + (l & 15);
        wp[idx] = f2bf(W2[k * Edim + n]);
    } else if (idx < 36864) {
        int t = idx - 20480;
        int nt = t >> 11, ks = (t >> 9) & 3, l = (t >> 3) & 63, j = t & 7;
        int k = ks * 32 + 8 * (l >> 4) + j, n = nt * 16 + (l & 15);
        wp[idx] = f2bf(W3[k * Edim + n]);
    } else {
        int t = idx - 36864;              // 0..767
        int lay = t >> 8;                 // 256 floats per layer
        int e   = t & 255;
        int nt  = e >> 5;                 // 32 per nt (16 cl x 2 comp)
        int cl  = (e >> 1) & 15;
        int comp = e & 1;
        const float* g  = (lay == 0) ? g1  : (lay == 1) ? g2  : g3;
        const float* be = (lay == 0) ? be1 : (lay == 1) ? be2 : be3;
        float v = comp ? be[nt*16 + cl] : g[nt*16 + cl];
        ((float*)wp)[18432 + t] = v;
    }
}

// LayerNorm + GELU on the wave-private accumulator (one point).
// D layout per 16x16 tile: value j of lane l is H[row = 4*(l>>4) + j][col = nt*16 + (l&15)]
// Row-reduction via packed DPP rot-adds; elementwise math on packed f32x2 (v_pk_*).
// gbeL: per-layer {gamma, beta} pairs, indexed [nt*16 + cl].
__device__ __forceinline__ void ln_gelu_acc(
    f32x4 acc[NT], const float2* __restrict__ gbeL, int lane)
{
    const int cl = lane & 15;
    f32x2 s01 = {0.f,0.f}, s23 = {0.f,0.f}, q01 = {0.f,0.f}, q23 = {0.f,0.f};
    #pragma unroll
    for (int nt = 0; nt < NT; ++nt) {
        f32x2 a01 = { acc[nt][0], acc[nt][1] };
        f32x2 a23 = { acc[nt][2], acc[nt][3] };
        s01 += a01;  q01 += a01 * a01;      // pk_add / pk_fma
        s23 += a23;  q23 += a23 * a23;
    }
    #define ROTSTEP(C) {                                                     \
        f32x2 t_;                                                            \
        t_.x = dpp_f32<C>(s01.x); t_.y = dpp_f32<C>(s01.y); s01 += t_;       \
        t_.x = dpp_f32<C>(s23.x); t_.y = dpp_f32<C>(s23.y); s23 += t_;       \
        t_.x = dpp_f32<C>(q01.x); t_.y = dpp_f32<C>(q01.y); q01 += t_;       \
        t_.x = dpp_f32<C>(q23.x); t_.y = dpp_f32<C>(q23.y); q23 += t_;       \
    }
    ROTSTEP(0x121) ROTSTEP(0x122) ROTSTEP(0x124) ROTSTEP(0x128)
    #undef ROTSTEP

    const f32x2 inv128 = { 1.0f/128.0f, 1.0f/128.0f };
    f32x2 m01 = s01 * inv128, m23 = s23 * inv128;
    f32x2 v01 = q01 * inv128 - m01 * m01;
    f32x2 v23 = q23 * inv128 - m23 * m23;
    f32x2 r01 = { __builtin_amdgcn_rsqf(v01.x + LN_EPS), __builtin_amdgcn_rsqf(v01.y + LN_EPS) };
    f32x2 r23 = { __builtin_amdgcn_rsqf(v23.x + LN_EPS), __builtin_amdgcn_rsqf(v23.y + LN_EPS) };

    #pragma unroll
    for (int nt = 0; nt < NT; ++nt) {
        const float2 gb = gbeL[nt*16 + cl];       // one dwordx2: {gamma, beta}
        const f32x2 gg = { gb.x, gb.x }, bb = { gb.y, gb.y };
        f32x2 a01 = { acc[nt][0], acc[nt][1] };
        f32x2 a23 = { acc[nt][2], acc[nt][3] };
        f32x2 w01 = (a01 - m01) * r01;
        f32x2 w23 = (a23 - m23) * r23;
        w01 = w01 * gg + bb;                // pk_fma
        w23 = w23 * gg + bb;
        w01 = gelu2(w01);
        w23 = gelu2(w23);
        acc[nt][0] = w01.x; acc[nt][1] = w01.y;
        acc[nt][2] = w23.x; acc[nt][3] = w23.y;
    }
}

// store acc (bf16 via HW cvt_pk) to swizzled H:
// elem col c of row r lives at r*128 + ((c>>3 ^ (r&7))<<3) + (c&7)
__device__ __forceinline__ void store_h(
    const f32x4 acc[NT], unsigned short* __restrict__ s_h, int wave, int lane)
{
    const int cl = lane & 15, gq = lane >> 4;
    const int rbase = 16*wave + 4*gq;
    #pragma unroll
    for (int nt = 0; nt < NT; ++nt) {
        const int col = nt*16 + cl;
        const int cb  = col >> 3;
        const unsigned r01 = cvt_pk_bf16(acc[nt][0], acc[nt][1]);
        const unsigned r23 = cvt_pk_bf16(acc[nt][2], acc[nt][3]);
        const int a0 = (rbase+0)*128 + ((cb ^ ((rbase+0) & 7)) << 3) + (col & 7);
        const int a1 = (rbase+1)*128 + ((cb ^ ((rbase+1) & 7)) << 3) + (col & 7);
        const int a2 = (rbase+2)*128 + ((cb ^ ((rbase+2) & 7)) << 3) + (col & 7);
        const int a3 = (rbase+3)*128 + ((cb ^ ((rbase+3) & 7)) << 3) + (col & 7);
        s_h[a0] = (unsigned short)(r01 & 0xFFFFu);
        s_h[a1] = (unsigned short)(r01 >> 16);
        s_h[a2] = (unsigned short)(r23 & 0xFFFFu);
        s_h[a3] = (unsigned short)(r23 >> 16);
    }
}

__global__ __launch_bounds__(128, 4) void edgeconv_mfma(
    const float* __restrict__ x,
    const unsigned short* __restrict__ wp,
    const float* __restrict__ b1, const float* __restrict__ b2,
    const float* __restrict__ b3,
    float* __restrict__ out)
{
    const int tid  = threadIdx.x;
    const int wave = tid >> 6, lane = tid & 63;
    const int bp = blockIdx.x;
    const int b  = bp >> 8;              // 256 blocks per batch element
    const int n0 = (bp & 255) * PTS;
    const int n  = n0 + wave;            // this wave's point

    // only LDS: wave-private H rows (wave w owns rows 16w..16w+15). No barriers anywhere.
    __shared__ __align__(16) unsigned short s_h[32 * 128];         // 8 KB, XOR-swizzled

    const float* __restrict__ xb = x + (size_t)b * (Ndim * Ddim);
    const float2* __restrict__ gbep = (const float2*)((const float*)wp + 18432);
    const int cl = lane & 15, gq = lane >> 4;

    // ---- KNN for this wave's point. Exact fp32 mul/mul/add; lex (d2, idx) order.
    //      Lane cl captures the cl-th selected neighbor index in my_nb.
    unsigned my_nb = 0;
    {
        const float qx = xb[n * Ddim + 8], qy = xb[n * Ddim + 9];
        unsigned long long key[8];
        #pragma unroll
        for (int c = 0; c < 8; ++c) {
            int j = c * 64 + lane;
            const float2 p2 = *(const float2*)(xb + j * Ddim + 8);
            float dx = __fsub_rn(qx, p2.x);
            float dy = __fsub_rn(qy, p2.y);
            float d2 = __fadd_rn(__fmul_rn(dx,dx), __fmul_rn(dy,dy));
            key[c] = ((unsigned long long)__float_as_uint(d2) << 32) | (unsigned)j;
        }
        // lane-local ascending sort of 8 keys (Batcher odd-even mergesort, 19 CE)
        #define CE(A,B) { bool c_ = key[A] < key[B];                          \
                          unsigned long long lo_ = c_ ? key[A] : key[B];      \
                          unsigned long long hi_ = c_ ? key[B] : key[A];      \
                          key[A] = lo_; key[B] = hi_; }
        CE(0,1) CE(2,3) CE(4,5) CE(6,7)
        CE(0,2) CE(1,3) CE(4,6) CE(5,7)
        CE(1,2) CE(5,6)
        CE(0,4) CE(1,5) CE(2,6) CE(3,7)
        CE(2,4) CE(3,5)
        CE(1,2) CE(3,4) CE(5,6)
        #undef CE

        unsigned d2h[8], idxh[8];
        #pragma unroll
        for (int c = 0; c < 8; ++c) {
            d2h[c]  = (unsigned)(key[c] >> 32);
            idxh[c] = (unsigned)key[c];
        }

        #pragma unroll
        for (int sel = 0; sel < Kdim; ++sel) {
            // wave-min of head d2: u32 only (1 v_min_u32 per stage)
            unsigned m = d2h[0];
            m = min_u32(m, dpp_u32<0x121>(m));
            m = min_u32(m, dpp_u32<0x122>(m));
            m = min_u32(m, dpp_u32<0x124>(m));
            m = min_u32(m, dpp_u32<0x128>(m));
            m = min_u32(m, dpp_u32_keep<0x142>(m));   // row1/3 <- min with row0/2
            m = min_u32(m, dpp_u32_keep<0x143>(m));   // upper half <- min with lane31
            const unsigned gmin = (unsigned)__builtin_amdgcn_readlane((int)m, 63);

            // tie resolution: wave-uniform branch, multi-tie is ~1e-4 rare
            const unsigned long long tied = __ballot(d2h[0] == gmin);
            unsigned widx;
            if (__popcll(tied) == 1) {
                const int s = (int)(__ffsll((long long)tied) - 1);
                widx = (unsigned)__builtin_amdgcn_readlane((int)idxh[0], s);
            } else {
                unsigned t = (d2h[0] == gmin) ? idxh[0] : 0xFFFFFFFFu;
                t = min_u32(t, dpp_u32<0x121>(t));
                t = min_u32(t, dpp_u32<0x122>(t));
                t = min_u32(t, dpp_u32<0x124>(t));
                t = min_u32(t, dpp_u32<0x128>(t));
                t = min_u32(t, dpp_u32_keep<0x142>(t));
                t = min_u32(t, dpp_u32_keep<0x143>(t));
                widx = (unsigned)__builtin_amdgcn_readlane((int)t, 63);
            }
            if ((lane & 15) == sel) my_nb = widx;     // capture in all 4 quads
            if (sel < Kdim - 1) {
                if (d2h[0] == gmin && idxh[0] == widx) {   // unique owner pops head
                    d2h[0]=d2h[1]; d2h[1]=d2h[2]; d2h[2]=d2h[3]; d2h[3]=d2h[4];
                    d2h[4]=d2h[5]; d2h[5]=d2h[6]; d2h[6]=d2h[7]; d2h[7]=0xFFFFFFFFu;
                    idxh[0]=idxh[1]; idxh[1]=idxh[2]; idxh[2]=idxh[3]; idxh[3]=idxh[4];
                    idxh[4]=idxh[5]; idxh[5]=idxh[6]; idxh[6]=idxh[7];
                }
            }
        }
    }

    f32x4 acc[NT];

    // ================= Layer 1: feats(16x32) @ W1, A-fragment built in registers =================
    {
        const int off8 = (gq & 1) * 8;
        const float* pc = xb + n * Ddim + off8;
        const float* pn = xb + (int)my_nb * Ddim + off8;
        float4 c0 = *(const float4*)(pc);
        float4 c1 = *(const float4*)(pc + 4);
        float4 v0 = *(const float4*)(pn);
        float4 v1 = *(const float4*)(pn + 4);
        const bool diff = (gq >= 2);
        float e0 = diff ? (v0.x - c0.x) : c0.x;
        float e1 = diff ? (v0.y - c0.y) : c0.y;
        float e2 = diff ? (v0.z - c0.z) : c0.z;
        float e3 = diff ? (v0.w - c0.w) : c0.w;
        float e4 = diff ? (v1.x - c1.x) : c1.x;
        float e5 = diff ? (v1.y - c1.y) : c1.y;
        float e6 = diff ? (v1.z - c1.z) : c1.z;
        float e7 = diff ? (v1.w - c1.w) : c1.w;
        union { unsigned u[4]; bf16x8 v; } a1u;
        a1u.u[0] = cvt_pk_bf16(e0, e1);
        a1u.u[1] = cvt_pk_bf16(e2, e3);
        a1u.u[2] = cvt_pk_bf16(e4, e5);
        a1u.u[3] = cvt_pk_bf16(e6, e7);
        const bf16x8 a1 = a1u.v;

        #pragma unroll
        for (int nt = 0; nt < NT; ++nt) {
            const float bv = b1[nt*16 + cl];
            bf16x8 bfr = *(const bf16x8*)(wp + (nt*64 + lane)*8);
            f32x4 c = {bv, bv, bv, bv};
            acc[nt] = __builtin_amdgcn_mfma_f32_16x16x32_bf16(a1, bfr, c, 0, 0, 0);
        }
    }
    ln_gelu_acc(acc, gbep, lane);
    store_h(acc, s_h, wave, lane);

    // ================= Layers 2 and 3: H(16x128) @ W(128x128) =================
    #pragma unroll 1
    for (int layer = 0; layer < 2; ++layer) {
        const unsigned short* wpL = wp + (layer == 0 ? 4096 : 20480);
        const float* bL = (layer == 0) ? b2 : b3;
        const float2* gbeL = gbep + (layer == 0 ? 128 : 256);

        bf16x8 a[KS2];
        {
            const int row = 16*wave + cl;
            #pragma unroll
            for (int ks = 0; ks < KS2; ++ks) {
                const int cb = ks*4 + gq;
                a[ks] = *(const bf16x8*)(&s_h[row*128 + ((cb ^ (row & 7)) << 3)]);
            }
        }
        #pragma unroll
        for (int nt = 0; nt < NT; ++nt) {
            const float bv = bL[nt*16 + cl];
            f32x4 c = {bv, bv, bv, bv};
            #pragma unroll
            for (int ks = 0; ks < KS2; ++ks) {
                bf16x8 bfr = *(const bf16x8*)(wpL + ((nt*KS2 + ks)*64 + lane)*8);
                c = __builtin_amdgcn_mfma_f32_16x16x32_bf16(a[ks], bfr, c, 0, 0, 0);
            }
            acc[nt] = c;
        }
        ln_gelu_acc(acc, gbeL, lane);
        if (layer == 0) store_h(acc, s_h, wave, lane);
    }

    // ================= mean over K=16 rows, write out =================
    #pragma unroll
    for (int nt = 0; nt < NT; ++nt) {
        f32x2 p = { acc[nt][0], acc[nt][1] };
        f32x2 q = { acc[nt][2], acc[nt][3] };
        f32x2 h = p + q;                    // pk_add
        float sv = h.x + h.y;
        sv += __shfl_xor(sv, 16, 64);
        sv += __shfl_xor(sv, 32, 64);
        if (gq == (nt >> 1))    // 16 lanes of the owning quad write 64B
            out[((size_t)b * Ndim + n) * Edim + nt*16 + cl] = sv * (1.0f/16.0f);
    }
}

extern "C" void kernel_launch(void* const* d_in, const int* in_sizes, int n_in,
                              void* d_out, int out_size, void* d_ws, size_t ws_size,
                              hipStream_t stream)
{
    const float* x   = (const float*)d_in[0];
    const float* W1  = (const float*)d_in[1];
    const float* b1  = (const float*)d_in[2];
    const float* g1  = (const float*)d_in[3];
    const float* be1 = (const float*)d_in[4];
    const float* W2  = (const float*)d_in[5];
    const float* b2  = (const float*)d_in[6];
    const float* g2  = (const float*)d_in[7];
    const float* be2 = (const float*)d_in[8];
    const float* W3  = (const float*)d_in[9];
    const float* b3  = (const float*)d_in[10];
    const float* g3  = (const float*)d_in[11];
    const float* be3 = (const float*)d_in[12];
    float* out = (float*)d_out;
    unsigned short* wp = (unsigned short*)d_ws;

    hipLaunchKernelGGL(pack_w_kernel, dim3(147), dim3(256), 0, stream,
                       W1, W2, W3, g1, be1, g2, be2, g3, be3, wp);
    hipLaunchKernelGGL(edgeconv_mfma, dim3((Bdim * Ndim) / PTS), dim3(128), 0, stream,
                       x, wp, b1, b2, b3, out);
}

// Round 13
// 163.607 us; speedup vs baseline: 1.0653x; 1.0516x over previous
//
#include <hip/hip_runtime.h>
#include <math.h>

#define Bdim 64
#define Ndim 512
#define Ddim 16
#define Kdim 16
#define Edim 128
#define LN_EPS 1e-5f

#define PTS   4     // points per block, TWO points per wave (ILP)
#define NT    8     // 16-wide N tiles over E=128
#define KS2   4     // 32-deep K steps over E=128

typedef __attribute__((ext_vector_type(8))) short bf16x8;
typedef __attribute__((ext_vector_type(4))) float f32x4;
typedef __attribute__((ext_vector_type(2))) float f32x2;

#if __has_builtin(__builtin_amdgcn_exp2f)
#define EXP2F __builtin_amdgcn_exp2f
#else
#define EXP2F exp2f
#endif

// ---- DPP helpers (pure VALU, no LDS) ----
// row_ror:N = 0x120|N ; ROW_BCAST15 = 0x142 ; ROW_BCAST31 = 0x143
template<int CTRL>
__device__ __forceinline__ unsigned dpp_u32(unsigned v) {
    return (unsigned)__builtin_amdgcn_update_dpp(0, (int)v, CTRL, 0xF, 0xF, true);
}
template<int CTRL>
__device__ __forceinline__ unsigned dpp_u32_keep(unsigned v) {
    return (unsigned)__builtin_amdgcn_update_dpp((int)v, (int)v, CTRL, 0xF, 0xF, false);
}
template<int CTRL>
__device__ __forceinline__ float dpp_f32(float v) {
    return __int_as_float(__builtin_amdgcn_update_dpp(0, __float_as_int(v), CTRL, 0xF, 0xF, true));
}
__device__ __forceinline__ unsigned min_u32(unsigned a, unsigned b) { return (b < a) ? b : a; }

// RNE float -> bf16 bits (used only in the tiny pack kernel)
__device__ __forceinline__ unsigned short f2bf(float f) {
    unsigned u = __float_as_uint(f);
    unsigned r = (u + 0x7FFFu + ((u >> 16) & 1u)) >> 16;
    return (unsigned short)r;
}

// HW packed f32->bf16 (RNE): lo16 = bf16(a), hi16 = bf16(b)
__device__ __forceinline__ unsigned cvt_pk_bf16(float a, float b) {
    unsigned r;
    asm("v_cvt_pk_bf16_f32 %0, %1, %2" : "=v"(r) : "v"(a), "v"(b));
    return r;
}

// packed GELU (tanh-form via sigmoid, exp folded to native 2^x) — R10's best-measured version
__device__ __forceinline__ f32x2 gelu2(f32x2 x) {
    f32x2 x2 = x * x;
    f32x2 t  = x2 * (f32x2){-0.10294324f, -0.10294324f}
                  + (f32x2){-2.30220821f, -2.30220821f};
    f32x2 z  = x * t;
    f32x2 e  = { EXP2F(z.x), EXP2F(z.y) };
    f32x2 d  = e + (f32x2){1.0f, 1.0f};
    f32x2 r  = { __builtin_amdgcn_rcpf(d.x), __builtin_amdgcn_rcpf(d.y) };
    return x * r;
}

// ---------------- weight pre-pack (identical to R10) ----------------
__global__ __launch_bounds__(256) void pack_w_kernel(
    const float* __restrict__ W1, const float* __restrict__ W2,
    const float* __restrict__ W3,
    const float* __restrict__ g1, const float* __restrict__ be1,
    const float* __restrict__ g2, const float* __restrict__ be2,
    const float* __restrict__ g3, const float* __restrict__ be3,
    unsigned short* __restrict__ wp)
{
    int idx = blockIdx.x * 256 + threadIdx.x;
    if (idx >= 37632) return;
    if (idx < 4096) {
        int t = idx;
        int nt = t >> 9, l = (t >> 3) & 63, j = t & 7;
        int k = 8 * (l >> 4) + j, n = nt * 16 + (l & 15);
        wp[idx] = f2bf(W1[k * Edim + n]);
    } else if (idx < 20480) {
        int t = idx - 4096;
        int nt = t >> 11, ks = (t >> 9) & 3, l = (t >> 3) & 63, j = t & 7;
        int k = ks * 32 + 8 * (l >> 4) + j, n = nt * 16 + (l & 15);
        wp[idx] = f2bf(W2[k * Edim + n]);
    } else if (idx < 36864) {
        int t = idx - 20480;
        int nt = t >> 11, ks = (t >> 9) & 3, l = (t >> 3) & 63, j = t & 7;
        int k = ks * 32 + 8 * (l >> 4) + j, n = nt * 16 + (l & 15);
        wp[idx] = f2bf(W3[k * Edim + n]);
    } else {
        int t = idx - 36864;              // 0..767
        int lay = t >> 8;
        int e   = t & 255;
        int nt  = e >> 5;
        int cl  = (e >> 1) & 15;
        int comp = e & 1;
        const float* g  = (lay == 0) ? g1  : (lay == 1) ? g2  : g3;
        const float* be = (lay == 0) ? be1 : (lay == 1) ? be2 : be3;
        float v = comp ? be[nt*16 + cl] : g[nt*16 + cl];
        ((float*)wp)[18432 + t] = v;
    }
}

// one tournament round: wave-min on head d2 (u32 DPP tree), exact (d2,idx) lex via
// always-run idx min-tree (branchless, interleaves with the other point's round).
__device__ __forceinline__ void knn_round(
    unsigned (&d2h)[8], unsigned (&idxh)[8], unsigned &my_nb, int sel, int lane, bool pop)
{
    unsigned m = d2h[0];
    m = min_u32(m, dpp_u32<0x121>(m));
    m = min_u32(m, dpp_u32<0x122>(m));
    m = min_u32(m, dpp_u32<0x124>(m));
    m = min_u32(m, dpp_u32<0x128>(m));
    m = min_u32(m, dpp_u32_keep<0x142>(m));
    m = min_u32(m, dpp_u32_keep<0x143>(m));
    const unsigned gmin = (unsigned)__builtin_amdgcn_readlane((int)m, 63);

    unsigned t = (d2h[0] == gmin) ? idxh[0] : 0xFFFFFFFFu;
    t = min_u32(t, dpp_u32<0x121>(t));
    t = min_u32(t, dpp_u32<0x122>(t));
    t = min_u32(t, dpp_u32<0x124>(t));
    t = min_u32(t, dpp_u32<0x128>(t));
    t = min_u32(t, dpp_u32_keep<0x142>(t));
    t = min_u32(t, dpp_u32_keep<0x143>(t));
    const unsigned widx = (unsigned)__builtin_amdgcn_readlane((int)t, 63);

    if ((lane & 15) == sel) my_nb = widx;
    if (pop) {
        if (d2h[0] == gmin && idxh[0] == widx) {   // unique owner pops sorted head
            d2h[0]=d2h[1]; d2h[1]=d2h[2]; d2h[2]=d2h[3]; d2h[3]=d2h[4];
            d2h[4]=d2h[5]; d2h[5]=d2h[6]; d2h[6]=d2h[7]; d2h[7]=0xFFFFFFFFu;
            idxh[0]=idxh[1]; idxh[1]=idxh[2]; idxh[2]=idxh[3]; idxh[3]=idxh[4];
            idxh[4]=idxh[5]; idxh[5]=idxh[6]; idxh[6]=idxh[7];
        }
    }
}

// LayerNorm + GELU on one point's accumulator (identical math to R10)
__device__ __forceinline__ void ln_gelu_acc(
    f32x4 (&acc)[NT], const float2* __restrict__ gbeL, int lane)
{
    const int cl = lane & 15;
    f32x2 s01 = {0.f,0.f}, s23 = {0.f,0.f}, q01 = {0.f,0.f}, q23 = {0.f,0.f};
    #pragma unroll
    for (int nt = 0; nt < NT; ++nt) {
        f32x2 a01 = { acc[nt][0], acc[nt][1] };
        f32x2 a23 = { acc[nt][2], acc[nt][3] };
        s01 += a01;  q01 += a01 * a01;
        s23 += a23;  q23 += a23 * a23;
    }
    #define ROTSTEP(C) {                                                     \
        f32x2 t_;                                                            \
        t_.x = dpp_f32<C>(s01.x); t_.y = dpp_f32<C>(s01.y); s01 += t_;       \
        t_.x = dpp_f32<C>(s23.x); t_.y = dpp_f32<C>(s23.y); s23 += t_;       \
        t_.x = dpp_f32<C>(q01.x); t_.y = dpp_f32<C>(q01.y); q01 += t_;       \
        t_.x = dpp_f32<C>(q23.x); t_.y = dpp_f32<C>(q23.y); q23 += t_;       \
    }
    ROTSTEP(0x121) ROTSTEP(0x122) ROTSTEP(0x124) ROTSTEP(0x128)
    #undef ROTSTEP

    const f32x2 inv128 = { 1.0f/128.0f, 1.0f/128.0f };
    f32x2 m01 = s01 * inv128, m23 = s23 * inv128;
    f32x2 v01 = q01 * inv128 - m01 * m01;
    f32x2 v23 = q23 * inv128 - m23 * m23;
    f32x2 r01 = { __builtin_amdgcn_rsqf(v01.x + LN_EPS), __builtin_amdgcn_rsqf(v01.y + LN_EPS) };
    f32x2 r23 = { __builtin_amdgcn_rsqf(v23.x + LN_EPS), __builtin_amdgcn_rsqf(v23.y + LN_EPS) };

    #pragma unroll
    for (int nt = 0; nt < NT; ++nt) {
        const float2 gb = gbeL[nt*16 + cl];
        const f32x2 gg = { gb.x, gb.x }, bb = { gb.y, gb.y };
        f32x2 a01 = { acc[nt][0], acc[nt][1] };
        f32x2 a23 = { acc[nt][2], acc[nt][3] };
        f32x2 w01 = (a01 - m01) * r01;
        f32x2 w23 = (a23 - m23) * r23;
        w01 = w01 * gg + bb;
        w23 = w23 * gg + bb;
        w01 = gelu2(w01);
        w23 = gelu2(w23);
        acc[nt][0] = w01.x; acc[nt][1] = w01.y;
        acc[nt][2] = w23.x; acc[nt][3] = w23.y;
    }
}

// store one point's acc (bf16 via cvt_pk) to swizzled H rows [rbase0 .. rbase0+15]
__device__ __forceinline__ void store_h(
    const f32x4 (&acc)[NT], unsigned short* __restrict__ s_h, int rbase0, int lane)
{
    const int cl = lane & 15, gq = lane >> 4;
    const int rbase = rbase0 + 4*gq;
    #pragma unroll
    for (int nt = 0; nt < NT; ++nt) {
        const int col = nt*16 + cl;
        const int cb  = col >> 3;
        const unsigned r01 = cvt_pk_bf16(acc[nt][0], acc[nt][1]);
        const unsigned r23 = cvt_pk_bf16(acc[nt][2], acc[nt][3]);
        const int a0 = (rbase+0)*128 + ((cb ^ ((rbase+0) & 7)) << 3) + (col & 7);
        const int a1 = (rbase+1)*128 + ((cb ^ ((rbase+1) & 7)) << 3) + (col & 7);
        const int a2 = (rbase+2)*128 + ((cb ^ ((rbase+2) & 7)) << 3) + (col & 7);
        const int a3 = (rbase+3)*128 + ((cb ^ ((rbase+3) & 7)) << 3) + (col & 7);
        s_h[a0] = (unsigned short)(r01 & 0xFFFFu);
        s_h[a1] = (unsigned short)(r01 >> 16);
        s_h[a2] = (unsigned short)(r23 & 0xFFFFu);
        s_h[a3] = (unsigned short)(r23 >> 16);
    }
}

__global__ __launch_bounds__(128, 3) void edgeconv_mfma(
    const float* __restrict__ x,
    const unsigned short* __restrict__ wp,
    const float* __restrict__ b1, const float* __restrict__ b2,
    const float* __restrict__ b3,
    float* __restrict__ out)
{
    const int tid  = threadIdx.x;
    const int wave = tid >> 6, lane = tid & 63;
    const int bp = blockIdx.x;
    const int b  = bp >> 7;              // 128 blocks per batch element
    const int n0 = (bp & 127) * PTS;
    const int nA = n0 + 2*wave;          // this wave's two points
    const int nB = nA + 1;

    // wave-private H rows (wave w owns rows 32w..32w+31). No barriers anywhere.
    __shared__ __align__(16) unsigned short s_h[64 * 128];         // 16 KB, XOR-swizzled

    const float* __restrict__ xb = x + (size_t)b * (Ndim * Ddim);
    const float2* __restrict__ gbep = (const float2*)((const float*)wp + 18432);
    const int cl = lane & 15, gq = lane >> 4;

    // ---- KNN for both points, interleaved tournaments. Exact fp32 mul/mul/add,
    //      lex (d2, idx) via u64 sort + branchless (d2-min, idx-min) rounds.
    unsigned my_nbA = 0, my_nbB = 0;
    unsigned d2A[8], ixA[8], d2B[8], ixB[8];
    {
        const float qxA = xb[nA * Ddim + 8], qyA = xb[nA * Ddim + 9];
        const float qxB = xb[nB * Ddim + 8], qyB = xb[nB * Ddim + 9];
        unsigned long long keyA[8], keyB[8];
        #pragma unroll
        for (int c = 0; c < 8; ++c) {
            int j = c * 64 + lane;
            const float2 p2 = *(const float2*)(xb + j * Ddim + 8);  // shared candidate load
            float dxA = __fsub_rn(qxA, p2.x), dyA = __fsub_rn(qyA, p2.y);
            float dxB = __fsub_rn(qxB, p2.x), dyB = __fsub_rn(qyB, p2.y);
            float dA = __fadd_rn(__fmul_rn(dxA,dxA), __fmul_rn(dyA,dyA));
            float dB = __fadd_rn(__fmul_rn(dxB,dxB), __fmul_rn(dyB,dyB));
            keyA[c] = ((unsigned long long)__float_as_uint(dA) << 32) | (unsigned)j;
            keyB[c] = ((unsigned long long)__float_as_uint(dB) << 32) | (unsigned)j;
        }
        // lane-local ascending sorts (Batcher odd-even mergesort, 19 CE each; independent)
        #define CE(K,A,B) { bool c_ = K[A] < K[B];                            \
                            unsigned long long lo_ = c_ ? K[A] : K[B];        \
                            unsigned long long hi_ = c_ ? K[B] : K[A];        \
                            K[A] = lo_; K[B] = hi_; }
        #define SORT8(K) CE(K,0,1) CE(K,2,3) CE(K,4,5) CE(K,6,7)              \
                         CE(K,0,2) CE(K,1,3) CE(K,4,6) CE(K,5,7)              \
                         CE(K,1,2) CE(K,5,6)                                  \
                         CE(K,0,4) CE(K,1,5) CE(K,2,6) CE(K,3,7)              \
                         CE(K,2,4) CE(K,3,5)                                  \
                         CE(K,1,2) CE(K,3,4) CE(K,5,6)
        SORT8(keyA)
        SORT8(keyB)
        #undef SORT8
        #undef CE
        #pragma unroll
        for (int c = 0; c < 8; ++c) {
            d2A[c] = (unsigned)(keyA[c] >> 32);  ixA[c] = (unsigned)keyA[c];
            d2B[c] = (unsigned)(keyB[c] >> 32);  ixB[c] = (unsigned)keyB[c];
        }
    }
    #pragma unroll
    for (int sel = 0; sel < Kdim; ++sel) {
        const bool pop = (sel < Kdim - 1);
        knn_round(d2A, ixA, my_nbA, sel, lane, pop);   // two independent chains —
        knn_round(d2B, ixB, my_nbB, sel, lane, pop);   // scheduler interleaves them
    }

    f32x4 acc[2][NT];

    // ================= Layer 1: feats(16x32) @ W1, A-fragments in registers =================
    {
        const int off8 = (gq & 1) * 8;
        const bool diff = (gq >= 2);
        bf16x8 a1[2];
        #pragma unroll
        for (int mt = 0; mt < 2; ++mt) {
            const int n = (mt == 0) ? nA : nB;
            const unsigned nb = (mt == 0) ? my_nbA : my_nbB;
            const float* pc = xb + n * Ddim + off8;
            const float* pn = xb + (int)nb * Ddim + off8;
            float4 c0 = *(const float4*)(pc);
            float4 c1 = *(const float4*)(pc + 4);
            float4 v0 = *(const float4*)(pn);
            float4 v1 = *(const float4*)(pn + 4);
            float e0 = diff ? (v0.x - c0.x) : c0.x;
            float e1 = diff ? (v0.y - c0.y) : c0.y;
            float e2 = diff ? (v0.z - c0.z) : c0.z;
            float e3 = diff ? (v0.w - c0.w) : c0.w;
            float e4 = diff ? (v1.x - c1.x) : c1.x;
            float e5 = diff ? (v1.y - c1.y) : c1.y;
            float e6 = diff ? (v1.z - c1.z) : c1.z;
            float e7 = diff ? (v1.w - c1.w) : c1.w;
            union { unsigned u[4]; bf16x8 v; } a1u;
            a1u.u[0] = cvt_pk_bf16(e0, e1);
            a1u.u[1] = cvt_pk_bf16(e2, e3);
            a1u.u[2] = cvt_pk_bf16(e4, e5);
            a1u.u[3] = cvt_pk_bf16(e6, e7);
            a1[mt] = a1u.v;
        }
        #pragma unroll
        for (int nt = 0; nt < NT; ++nt) {
            const float bv = b1[nt*16 + cl];                       // shared across mt
            bf16x8 bfr = *(const bf16x8*)(wp + (nt*64 + lane)*8);  // shared across mt
            f32x4 c = {bv, bv, bv, bv};
            acc[0][nt] = __builtin_amdgcn_mfma_f32_16x16x32_bf16(a1[0], bfr, c, 0, 0, 0);
            acc[1][nt] = __builtin_amdgcn_mfma_f32_16x16x32_bf16(a1[1], bfr, c, 0, 0, 0);
        }
    }
    ln_gelu_acc(acc[0], gbep, lane);
    ln_gelu_acc(acc[1], gbep, lane);
    store_h(acc[0], s_h, 32*wave +  0, lane);
    store_h(acc[1], s_h, 32*wave + 16, lane);

    // ================= Layers 2 and 3: H(32x128) @ W(128x128) =================
    #pragma unroll 1
    for (int layer = 0; layer < 2; ++layer) {
        const unsigned short* wpL = wp + (layer == 0 ? 4096 : 20480);
        const float* bL = (layer == 0) ? b2 : b3;
        const float2* gbeL = gbep + (layer == 0 ? 128 : 256);

        bf16x8 a[2][KS2];
        #pragma unroll
        for (int mt = 0; mt < 2; ++mt) {
            const int row = 32*wave + 16*mt + cl;
            #pragma unroll
            for (int ks = 0; ks < KS2; ++ks) {
                const int cb = ks*4 + gq;
                a[mt][ks] = *(const bf16x8*)(&s_h[row*128 + ((cb ^ (row & 7)) << 3)]);
            }
        }
        #pragma unroll
        for (int nt = 0; nt < NT; ++nt) {
            const float bv = bL[nt*16 + cl];                       // shared across mt
            bf16x8 bfr[KS2];
            #pragma unroll
            for (int ks = 0; ks < KS2; ++ks)                       // shared across mt
                bfr[ks] = *(const bf16x8*)(wpL + ((nt*KS2 + ks)*64 + lane)*8);
            #pragma unroll
            for (int mt = 0; mt < 2; ++mt) {
                f32x4 c = {bv, bv, bv, bv};
                #pragma unroll
                for (int ks = 0; ks < KS2; ++ks)
                    c = __builtin_amdgcn_mfma_f32_16x16x32_bf16(a[mt][ks], bfr[ks], c, 0, 0, 0);
                acc[mt][nt] = c;
            }
        }
        ln_gelu_acc(acc[0], gbeL, lane);
        ln_gelu_acc(acc[1], gbeL, lane);
        if (layer == 0) {
            store_h(acc[0], s_h, 32*wave +  0, lane);
            store_h(acc[1], s_h, 32*wave + 16, lane);
        }
    }

    // ================= mean over K=16 rows, write out =================
    #pragma unroll
    for (int mt = 0; mt < 2; ++mt) {
        const int n = (mt == 0) ? nA : nB;
        #pragma unroll
        for (int nt = 0; nt < NT; ++nt) {
            f32x2 p = { acc[mt][nt][0], acc[mt][nt][1] };
            f32x2 q = { acc[mt][nt][2], acc[mt][nt][3] };
            f32x2 h = p + q;
            float sv = h.x + h.y;
            sv += __shfl_xor(sv, 16, 64);
            sv += __shfl_xor(sv, 32, 64);
            if (gq == (nt >> 1))
                out[((size_t)b * Ndim + n) * Edim + nt*16 + cl] = sv * (1.0f/16.0f);
        }
    }
}

extern "C" void kernel_launch(void* const* d_in, const int* in_sizes, int n_in,
                              void* d_out, int out_size, void* d_ws, size_t ws_size,
                              hipStream_t stream)
{
    const float* x   = (const float*)d_in[0];
    const float* W1  = (const float*)d_in[1];
    const float* b1  = (const float*)d_in[2];
    const float* g1  = (const float*)d_in[3];
    const float* be1 = (const float*)d_in[4];
    const float* W2  = (const float*)d_in[5];
    const float* b2  = (const float*)d_in[6];
    const float* g2  = (const float*)d_in[7];
    const float* be2 = (const float*)d_in[8];
    const float* W3  = (const float*)d_in[9];
    const float* b3  = (const float*)d_in[10];
    const float* g3  = (const float*)d_in[11];
    const float* be3 = (const float*)d_in[12];
    float* out = (float*)d_out;
    unsigned short* wp = (unsigned short*)d_ws;

    hipLaunchKernelGGL(pack_w_kernel, dim3(147), dim3(256), 0, stream,
                       W1, W2, W3, g1, be1, g2, be2, g3, be3, wp);
    hipLaunchKernelGGL(edgeconv_mfma, dim3((Bdim * Ndim) / PTS), dim3(128), 0, stream,
                       x, wp, b1, b2, b3, out);
}

// Round 14
// 158.449 us; speedup vs baseline: 1.1000x; 1.0325x over previous
//
#include <hip/hip_runtime.h>
#include <math.h>

#define Bdim 64
#define Ndim 512
#define Ddim 16
#define Kdim 16
#define Edim 128
#define LN_EPS 1e-5f

#define PTS   2     // points per block, ONE point per wave
#define NT    8     // 16-wide N tiles over E=128
#define KS2   4     // 32-deep K steps over E=128

typedef __attribute__((ext_vector_type(8))) short bf16x8;
typedef __attribute__((ext_vector_type(4))) float f32x4;
typedef __attribute__((ext_vector_type(2))) float f32x2;

#if __has_builtin(__builtin_amdgcn_exp2f)
#define EXP2F __builtin_amdgcn_exp2f
#else
#define EXP2F exp2f
#endif

// ---- DPP helpers (pure VALU, no LDS) ----
// row_ror:N = 0x120|N ; ROW_BCAST15 = 0x142 ; ROW_BCAST31 = 0x143
template<int CTRL>
__device__ __forceinline__ unsigned dpp_u32(unsigned v) {
    return (unsigned)__builtin_amdgcn_update_dpp(0, (int)v, CTRL, 0xF, 0xF, true);
}
// keep-variant: lanes with no DPP source keep their own value (old = src, bound_ctrl=0)
template<int CTRL>
__device__ __forceinline__ unsigned dpp_u32_keep(unsigned v) {
    return (unsigned)__builtin_amdgcn_update_dpp((int)v, (int)v, CTRL, 0xF, 0xF, false);
}
template<int CTRL>
__device__ __forceinline__ float dpp_f32(float v) {
    return __int_as_float(__builtin_amdgcn_update_dpp(0, __float_as_int(v), CTRL, 0xF, 0xF, true));
}
__device__ __forceinline__ unsigned min_u32(unsigned a, unsigned b) { return (b < a) ? b : a; }

// RNE float -> bf16 bits (used only in the tiny pack kernel)
__device__ __forceinline__ unsigned short f2bf(float f) {
    unsigned u = __float_as_uint(f);
    unsigned r = (u + 0x7FFFu + ((u >> 16) & 1u)) >> 16;
    return (unsigned short)r;
}

// HW packed f32->bf16 (RNE): lo16 = bf16(a), hi16 = bf16(b)
__device__ __forceinline__ unsigned cvt_pk_bf16(float a, float b) {
    unsigned r;
    asm("v_cvt_pk_bf16_f32 %0, %1, %2" : "=v"(r) : "v"(a), "v"(b));
    return r;
}

// packed GELU (tanh-form via sigmoid, exp folded to native 2^x):
// gelu(x) ~= x * rcp(1 + 2^(x * (-2.30220821 - 0.10294324 x^2)))
__device__ __forceinline__ f32x2 gelu2(f32x2 x) {
    f32x2 x2 = x * x;
    f32x2 t  = x2 * (f32x2){-0.10294324f, -0.10294324f}
                  + (f32x2){-2.30220821f, -2.30220821f};
    f32x2 z  = x * t;
    f32x2 e  = { EXP2F(z.x), EXP2F(z.y) };
    f32x2 d  = e + (f32x2){1.0f, 1.0f};
    f32x2 r  = { __builtin_amdgcn_rcpf(d.x), __builtin_amdgcn_rcpf(d.y) };
    return x * r;
}

// ---------------- weight pre-pack ----------------
// wp[0..36863]  : bf16 B-fragments (layout as before)
// fp32 at float index 18432 (byte 73728): gbe pairs, float2
//   gbe[((lay*8 + nt)*16 + cl)] = { g[nt*16+cl], be[nt*16+cl] }   (768 floats)
__global__ __launch_bounds__(256) void pack_w_kernel(
    const float* __restrict__ W1, const float* __restrict__ W2,
    const float* __restrict__ W3,
    const float* __restrict__ g1, const float* __restrict__ be1,
    const float* __restrict__ g2, const float* __restrict__ be2,
    const float* __restrict__ g3, const float* __restrict__ be3,
    unsigned short* __restrict__ wp)
{
    int idx = blockIdx.x * 256 + threadIdx.x;
    if (idx >= 37632) return;
    if (idx < 4096) {
        int t = idx;
        int nt = t >> 9, l = (t >> 3) & 63, j = t & 7;
        int k = 8 * (l >> 4) + j, n = nt * 16 + (l & 15);
        wp[idx] = f2bf(W1[k * Edim + n]);
    } else if (idx < 20480) {
        int t = idx - 4096;
        int nt = t >> 11, ks = (t >> 9) & 3, l = (t >> 3) & 63, j = t & 7;
        int k = ks * 32 + 8 * (l >> 4) + j, n = nt * 16 + (l & 15);
        wp[idx] = f2bf(W2[k * Edim + n]);
    } else if (idx < 36864) {
        int t = idx - 20480;
        int nt = t >> 11, ks = (t >> 9) & 3, l = (t >> 3) & 63, j = t & 7;
        int k = ks * 32 + 8 * (l >> 4) + j, n = nt * 16 + (l & 15);
        wp[idx] = f2bf(W3[k * Edim + n]);
    } else {
        int t = idx - 36864;              // 0..767
        int lay = t >> 8;                 // 256 floats per layer
        int e   = t & 255;
        int nt  = e >> 5;                 // 32 per nt (16 cl x 2 comp)
        int cl  = (e >> 1) & 15;
        int comp = e & 1;
        const float* g  = (lay == 0) ? g1  : (lay == 1) ? g2  : g3;
        const float* be = (lay == 0) ? be1 : (lay == 1) ? be2 : be3;
        float v = comp ? be[nt*16 + cl] : g[nt*16 + cl];
        ((float*)wp)[18432 + t] = v;
    }
}

// LayerNorm + GELU on the wave-private accumulator (one point).
// D layout per 16x16 tile: value j of lane l is H[row = 4*(l>>4) + j][col = nt*16 + (l&15)]
// Row-reduction via packed DPP rot-adds; elementwise math on packed f32x2 (v_pk_*).
// gbeL: per-layer {gamma, beta} pairs, indexed [nt*16 + cl].
__device__ __forceinline__ void ln_gelu_acc(
    f32x4 acc[NT], const float2* __restrict__ gbeL, int lane)
{
    const int cl = lane & 15;
    f32x2 s01 = {0.f,0.f}, s23 = {0.f,0.f}, q01 = {0.f,0.f}, q23 = {0.f,0.f};
    #pragma unroll
    for (int nt = 0; nt < NT; ++nt) {
        f32x2 a01 = { acc[nt][0], acc[nt][1] };
        f32x2 a23 = { acc[nt][2], acc[nt][3] };
        s01 += a01;  q01 += a01 * a01;      // pk_add / pk_fma
        s23 += a23;  q23 += a23 * a23;
    }
    #define ROTSTEP(C) {                                                     \
        f32x2 t_;                                                            \
        t_.x = dpp_f32<C>(s01.x); t_.y = dpp_f32<C>(s01.y); s01 += t_;       \
        t_.x = dpp_f32<C>(s23.x); t_.y = dpp_f32<C>(s23.y); s23 += t_;       \
        t_.x = dpp_f32<C>(q01.x); t_.y = dpp_f32<C>(q01.y); q01 += t_;       \
        t_.x = dpp_f32<C>(q23.x); t_.y = dpp_f32<C>(q23.y); q23 += t_;       \
    }
    ROTSTEP(0x121) ROTSTEP(0x122) ROTSTEP(0x124) ROTSTEP(0x128)
    #undef ROTSTEP

    const f32x2 inv128 = { 1.0f/128.0f, 1.0f/128.0f };
    f32x2 m01 = s01 * inv128, m23 = s23 * inv128;
    f32x2 v01 = q01 * inv128 - m01 * m01;
    f32x2 v23 = q23 * inv128 - m23 * m23;
    f32x2 r01 = { __builtin_amdgcn_rsqf(v01.x + LN_EPS), __builtin_amdgcn_rsqf(v01.y + LN_EPS) };
    f32x2 r23 = { __builtin_amdgcn_rsqf(v23.x + LN_EPS), __builtin_amdgcn_rsqf(v23.y + LN_EPS) };

    #pragma unroll
    for (int nt = 0; nt < NT; ++nt) {
        const float2 gb = gbeL[nt*16 + cl];       // one dwordx2: {gamma, beta}
        const f32x2 gg = { gb.x, gb.x }, bb = { gb.y, gb.y };
        f32x2 a01 = { acc[nt][0], acc[nt][1] };
        f32x2 a23 = { acc[nt][2], acc[nt][3] };
        f32x2 w01 = (a01 - m01) * r01;
        f32x2 w23 = (a23 - m23) * r23;
        w01 = w01 * gg + bb;                // pk_fma
        w23 = w23 * gg + bb;
        w01 = gelu2(w01);
        w23 = gelu2(w23);
        acc[nt][0] = w01.x; acc[nt][1] = w01.y;
        acc[nt][2] = w23.x; acc[nt][3] = w23.y;
    }
}

// store acc (bf16 via HW cvt_pk) to swizzled H:
// elem col c of row r lives at r*128 + ((c>>3 ^ (r&7))<<3) + (c&7)
__device__ __forceinline__ void store_h(
    const f32x4 acc[NT], unsigned short* __restrict__ s_h, int wave, int lane)
{
    const int cl = lane & 15, gq = lane >> 4;
    const int rbase = 16*wave + 4*gq;
    #pragma unroll
    for (int nt = 0; nt < NT; ++nt) {
        const int col = nt*16 + cl;
        const int cb  = col >> 3;
        const unsigned r01 = cvt_pk_bf16(acc[nt][0], acc[nt][1]);
        const unsigned r23 = cvt_pk_bf16(acc[nt][2], acc[nt][3]);
        const int a0 = (rbase+0)*128 + ((cb ^ ((rbase+0) & 7)) << 3) + (col & 7);
        const int a1 = (rbase+1)*128 + ((cb ^ ((rbase+1) & 7)) << 3) + (col & 7);
        const int a2 = (rbase+2)*128 + ((cb ^ ((rbase+2) & 7)) << 3) + (col & 7);
        const int a3 = (rbase+3)*128 + ((cb ^ ((rbase+3) & 7)) << 3) + (col & 7);
        s_h[a0] = (unsigned short)(r01 & 0xFFFFu);
        s_h[a1] = (unsigned short)(r01 >> 16);
        s_h[a2] = (unsigned short)(r23 & 0xFFFFu);
        s_h[a3] = (unsigned short)(r23 >> 16);
    }
}

__global__ __launch_bounds__(128, 4) void edgeconv_mfma(
    const float* __restrict__ x,
    const unsigned short* __restrict__ wp,
    const float* __restrict__ b1, const float* __restrict__ b2,
    const float* __restrict__ b3,
    float* __restrict__ out)
{
    const int tid  = threadIdx.x;
    const int wave = tid >> 6, lane = tid & 63;
    const int bp = blockIdx.x;
    const int b  = bp >> 8;              // 256 blocks per batch element
    const int n0 = (bp & 255) * PTS;
    const int n  = n0 + wave;            // this wave's point

    // only LDS: wave-private H rows (wave w owns rows 16w..16w+15). No barriers anywhere.
    __shared__ __align__(16) unsigned short s_h[32 * 128];         // 8 KB, XOR-swizzled

    const float* __restrict__ xb = x + (size_t)b * (Ndim * Ddim);
    const float2* __restrict__ gbep = (const float2*)((const float*)wp + 18432);
    const int cl = lane & 15, gq = lane >> 4;

    // ---- KNN for this wave's point. Exact fp32 mul/mul/add; lex (d2, idx) order.
    //      Lane cl captures the cl-th selected neighbor index in my_nb.
    unsigned my_nb = 0;
    {
        const float qx = xb[n * Ddim + 8], qy = xb[n * Ddim + 9];
        unsigned long long key[8];
        #pragma unroll
        for (int c = 0; c < 8; ++c) {
            int j = c * 64 + lane;
            const float2 p2 = *(const float2*)(xb + j * Ddim + 8);
            float dx = __fsub_rn(qx, p2.x);
            float dy = __fsub_rn(qy, p2.y);
            float d2 = __fadd_rn(__fmul_rn(dx,dx), __fmul_rn(dy,dy));
            key[c] = ((unsigned long long)__float_as_uint(d2) << 32) | (unsigned)j;
        }
        // lane-local ascending sort of 8 keys (Batcher odd-even mergesort, 19 CE)
        #define CE(A,B) { bool c_ = key[A] < key[B];                          \
                          unsigned long long lo_ = c_ ? key[A] : key[B];      \
                          unsigned long long hi_ = c_ ? key[B] : key[A];      \
                          key[A] = lo_; key[B] = hi_; }
        CE(0,1) CE(2,3) CE(4,5) CE(6,7)
        CE(0,2) CE(1,3) CE(4,6) CE(5,7)
        CE(1,2) CE(5,6)
        CE(0,4) CE(1,5) CE(2,6) CE(3,7)
        CE(2,4) CE(3,5)
        CE(1,2) CE(3,4) CE(5,6)
        #undef CE

        unsigned d2h[8], idxh[8];
        #pragma unroll
        for (int c = 0; c < 8; ++c) {
            d2h[c]  = (unsigned)(key[c] >> 32);
            idxh[c] = (unsigned)key[c];
        }

        #pragma unroll
        for (int sel = 0; sel < Kdim; ++sel) {
            // wave-min of head d2: u32 only (1 v_min_u32 per stage)
            unsigned m = d2h[0];
            m = min_u32(m, dpp_u32<0x121>(m));
            m = min_u32(m, dpp_u32<0x122>(m));
            m = min_u32(m, dpp_u32<0x124>(m));
            m = min_u32(m, dpp_u32<0x128>(m));
            m = min_u32(m, dpp_u32_keep<0x142>(m));   // row1/3 <- min with row0/2
            m = min_u32(m, dpp_u32_keep<0x143>(m));   // upper half <- min with lane31
            const unsigned gmin = (unsigned)__builtin_amdgcn_readlane((int)m, 63);

            // tie resolution: wave-uniform branch, multi-tie is ~1e-4 rare
            const unsigned long long tied = __ballot(d2h[0] == gmin);
            unsigned widx;
            if (__popcll(tied) == 1) {
                const int s = (int)(__ffsll((long long)tied) - 1);
                widx = (unsigned)__builtin_amdgcn_readlane((int)idxh[0], s);
            } else {
                unsigned t = (d2h[0] == gmin) ? idxh[0] : 0xFFFFFFFFu;
                t = min_u32(t, dpp_u32<0x121>(t));
                t = min_u32(t, dpp_u32<0x122>(t));
                t = min_u32(t, dpp_u32<0x124>(t));
                t = min_u32(t, dpp_u32<0x128>(t));
                t = min_u32(t, dpp_u32_keep<0x142>(t));
                t = min_u32(t, dpp_u32_keep<0x143>(t));
                widx = (unsigned)__builtin_amdgcn_readlane((int)t, 63);
            }
            if ((lane & 15) == sel) my_nb = widx;     // capture in all 4 quads
            if (sel < Kdim - 1) {
                if (d2h[0] == gmin && idxh[0] == widx) {   // unique owner pops head
                    d2h[0]=d2h[1]; d2h[1]=d2h[2]; d2h[2]=d2h[3]; d2h[3]=d2h[4];
                    d2h[4]=d2h[5]; d2h[5]=d2h[6]; d2h[6]=d2h[7]; d2h[7]=0xFFFFFFFFu;
                    idxh[0]=idxh[1]; idxh[1]=idxh[2]; idxh[2]=idxh[3]; idxh[3]=idxh[4];
                    idxh[4]=idxh[5]; idxh[5]=idxh[6]; idxh[6]=idxh[7];
                }
            }
        }
    }

    f32x4 acc[NT];

    // ================= Layer 1: feats(16x32) @ W1, A-fragment built in registers =================
    {
        const int off8 = (gq & 1) * 8;
        const float* pc = xb + n * Ddim + off8;
        const float* pn = xb + (int)my_nb * Ddim + off8;
        float4 c0 = *(const float4*)(pc);
        float4 c1 = *(const float4*)(pc + 4);
        float4 v0 = *(const float4*)(pn);
        float4 v1 = *(const float4*)(pn + 4);
        const bool diff = (gq >= 2);
        float e0 = diff ? (v0.x - c0.x) : c0.x;
        float e1 = diff ? (v0.y - c0.y) : c0.y;
        float e2 = diff ? (v0.z - c0.z) : c0.z;
        float e3 = diff ? (v0.w - c0.w) : c0.w;
        float e4 = diff ? (v1.x - c1.x) : c1.x;
        float e5 = diff ? (v1.y - c1.y) : c1.y;
        float e6 = diff ? (v1.z - c1.z) : c1.z;
        float e7 = diff ? (v1.w - c1.w) : c1.w;
        union { unsigned u[4]; bf16x8 v; } a1u;
        a1u.u[0] = cvt_pk_bf16(e0, e1);
        a1u.u[1] = cvt_pk_bf16(e2, e3);
        a1u.u[2] = cvt_pk_bf16(e4, e5);
        a1u.u[3] = cvt_pk_bf16(e6, e7);
        const bf16x8 a1 = a1u.v;

        #pragma unroll
        for (int nt = 0; nt < NT; ++nt) {
            const float bv = b1[nt*16 + cl];
            bf16x8 bfr = *(const bf16x8*)(wp + (nt*64 + lane)*8);
            f32x4 c = {bv, bv, bv, bv};
            acc[nt] = __builtin_amdgcn_mfma_f32_16x16x32_bf16(a1, bfr, c, 0, 0, 0);
        }
    }
    ln_gelu_acc(acc, gbep, lane);
    store_h(acc, s_h, wave, lane);

    // ================= Layers 2 and 3: H(16x128) @ W(128x128) =================
    #pragma unroll 1
    for (int layer = 0; layer < 2; ++layer) {
        const unsigned short* wpL = wp + (layer == 0 ? 4096 : 20480);
        const float* bL = (layer == 0) ? b2 : b3;
        const float2* gbeL = gbep + (layer == 0 ? 128 : 256);

        bf16x8 a[KS2];
        {
            const int row = 16*wave + cl;
            #pragma unroll
            for (int ks = 0; ks < KS2; ++ks) {
                const int cb = ks*4 + gq;
                a[ks] = *(const bf16x8*)(&s_h[row*128 + ((cb ^ (row & 7)) << 3)]);
            }
        }
        #pragma unroll
        for (int nt = 0; nt < NT; ++nt) {
            const float bv = bL[nt*16 + cl];
            f32x4 c = {bv, bv, bv, bv};
            #pragma unroll
            for (int ks = 0; ks < KS2; ++ks) {
                bf16x8 bfr = *(const bf16x8*)(wpL + ((nt*KS2 + ks)*64 + lane)*8);
                c = __builtin_amdgcn_mfma_f32_16x16x32_bf16(a[ks], bfr, c, 0, 0, 0);
            }
            acc[nt] = c;
        }
        ln_gelu_acc(acc, gbeL, lane);
        if (layer == 0) store_h(acc, s_h, wave, lane);
    }

    // ================= mean over K=16 rows, write out =================
    #pragma unroll
    for (int nt = 0; nt < NT; ++nt) {
        f32x2 p = { acc[nt][0], acc[nt][1] };
        f32x2 q = { acc[nt][2], acc[nt][3] };
        f32x2 h = p + q;                    // pk_add
        float sv = h.x + h.y;
        sv += __shfl_xor(sv, 16, 64);
        sv += __shfl_xor(sv, 32, 64);
        if (gq == (nt >> 1))    // 16 lanes of the owning quad write 64B
            out[((size_t)b * Ndim + n) * Edim + nt*16 + cl] = sv * (1.0f/16.0f);
    }
}

extern "C" void kernel_launch(void* const* d_in, const int* in_sizes, int n_in,
                              void* d_out, int out_size, void* d_ws, size_t ws_size,
                              hipStream_t stream)
{
    const float* x   = (const float*)d_in[0];
    const float* W1  = (const float*)d_in[1];
    const float* b1  = (const float*)d_in[2];
    const float* g1  = (const float*)d_in[3];
    const float* be1 = (const float*)d_in[4];
    const float* W2  = (const float*)d_in[5];
    const float* b2  = (const float*)d_in[6];
    const float* g2  = (const float*)d_in[7];
    const float* be2 = (const float*)d_in[8];
    const float* W3  = (const float*)d_in[9];
    const float* b3  = (const float*)d_in[10];
    const float* g3  = (const float*)d_in[11];
    const float* be3 = (const float*)d_in[12];
    float* out = (float*)d_out;
    unsigned short* wp = (unsigned short*)d_ws;

    hipLaunchKernelGGL(pack_w_kernel, dim3(147), dim3(256), 0, stream,
                       W1, W2, W3, g1, be1, g2, be2, g3, be3, wp);
    hipLaunchKernelGGL(edgeconv_mfma, dim3((Bdim * Ndim) / PTS), dim3(128), 0, stream,
                       x, wp, b1, b2, b3, out);
}